// Round 5
// baseline (592.499 us; speedup 1.0000x reference)
//
#include <hip/hip_runtime.h>

// SlotAttention fused implementation (f32 hln).
//   - 6-layer linear stack folded into effective 66->128 affine (Wh, bh).
//   - k,v projections folded out of the N dimension:
//       q.k_n = (wk@q) . hln_n + q.bk ;  updates = (sum attn*hln)/den @ wv + bv
//   - hln = LN(h) materialized f32, layout [32 granules][NB][4 floats] (coalesced).
//   - slot init: JAX partitionable threefry (default in current JAX):
//       bits[i] = o0 ^ o1 of threefry2x32(key=(0,42), counter=(0, i))

#define B_  8
#define N_  32768
#define NB_ (B_ * N_)   // 262144 rows
#define D_  128
#define S_  8

typedef unsigned int u32;

// threefry2x32, key = (0, 42)  (jax.random.key(42))
__device__ inline void threefry42(u32 c0, u32 c1, u32& o0, u32& o1) {
    const u32 k0 = 0u, k1 = 42u, k2 = 0x1BD11BDAu ^ 0u ^ 42u;
    const u32 ks[3] = {k0, k1, k2};
    u32 x0 = c0 + k0, x1 = c1 + k1;
    const int rA[4] = {13, 15, 26, 6}, rB[4] = {17, 29, 16, 24};
#pragma unroll
    for (int i = 0; i < 5; i++) {
#pragma unroll
        for (int k = 0; k < 4; k++) {
            int r = (i & 1) ? rB[k] : rA[k];
            x0 += x1;
            x1 = (x1 << r) | (x1 >> (32 - r));
            x1 ^= x0;
        }
        x0 += ks[(i + 1) % 3];
        x1 += ks[(i + 2) % 3] + (u32)(i + 1);
    }
    o0 = x0; o1 = x1;
}

// jax uniform(-0.99999994, 1) -> sqrt(2)*erfinv  (XLA ErfInv32 polynomial)
__device__ inline float bits_to_normal(u32 b) {
    float f = __uint_as_float((b >> 9) | 0x3f800000u) - 1.0f;  // [0,1)
    const float lo = -0.99999994f;
    float r = fmaxf(lo, f * 1.99999994f + lo);
    float w = -log1pf(-r * r);
    float p;
    if (w < 5.0f) {
        w -= 2.5f;
        p = 2.81022636e-08f;
        p = fmaf(p, w, 3.43273939e-07f);
        p = fmaf(p, w, -3.5233877e-06f);
        p = fmaf(p, w, -4.39150654e-06f);
        p = fmaf(p, w, 0.00021858087f);
        p = fmaf(p, w, -0.00125372503f);
        p = fmaf(p, w, -0.00417768164f);
        p = fmaf(p, w, 0.246640727f);
        p = fmaf(p, w, 1.50140941f);
    } else {
        w = sqrtf(w) - 3.0f;
        p = -0.000200214257f;
        p = fmaf(p, w, 0.000100950558f);
        p = fmaf(p, w, 0.00134934322f);
        p = fmaf(p, w, -0.00367342844f);
        p = fmaf(p, w, 0.00573950773f);
        p = fmaf(p, w, -0.0076224613f);
        p = fmaf(p, w, 0.00943887047f);
        p = fmaf(p, w, 1.00167406f);
        p = fmaf(p, w, 2.83297682f);
    }
    return 1.41421356f * (p * r);
}

// 128-thread block sum (2 waves), red = 2-float shared scratch
__device__ inline float block128_sum(float v, float* red) {
#pragma unroll
    for (int o = 32; o; o >>= 1) v += __shfl_down(v, o);
    __syncthreads();
    if ((threadIdx.x & 63) == 0) red[threadIdx.x >> 6] = v;
    __syncthreads();
    return red[0] + red[1];
}

// LN(slot row) -> q -> qtilde(scaled), qc(scaled); zero vec/den accumulators.
__device__ void emit_q(float x, int bs,
                       const float* lnsg, const float* lnsb,
                       const float* wq, const float* bq,
                       const float* wk, const float* bk,
                       float* qt, float* qc, float* vec, float* den,
                       float* shA, float* red) {
    int t = threadIdx.x;
    float m = block128_sum(x, red) * (1.0f / 128.0f);
    float e = x - m;
    float var = block128_sum(e * e, red) * (1.0f / 128.0f);
    float inv = rsqrtf(var + 1e-5f);
    __syncthreads();
    shA[t] = fmaf(e * inv, lnsg[t], lnsb[t]);
    __syncthreads();
    float q = bq[t];
#pragma unroll 4
    for (int i = 0; i < 128; i++) q = fmaf(shA[i], wq[i * 128 + t], q);
    __syncthreads();
    shA[t] = q;
    __syncthreads();
    float a2 = 0.f;
#pragma unroll 4
    for (int j = 0; j < 128; j++) a2 = fmaf(wk[t * 128 + j], shA[j], a2);
    const float scale = 0.08838834764831845f;  // 128^-0.5
    qt[bs * 128 + t] = a2 * scale;
    float pr = block128_sum(shA[t] * bk[t], red);
    if (t == 0) { qc[bs] = pr * scale; den[bs] = 0.f; }
    vec[bs * 128 + t] = 0.f;
}

// ---------- K1: fold weights, init slots ----------

__global__ __launch_bounds__(256) void k1_setup(
    const float* __restrict__ w0, const float* __restrict__ b0,
    const float* __restrict__ w1, const float* __restrict__ b1,
    const float* __restrict__ w2, const float* __restrict__ b2,
    const float* __restrict__ w3, const float* __restrict__ b3,
    const float* __restrict__ w4, const float* __restrict__ b4,
    const float* __restrict__ w5, const float* __restrict__ b5,
    const float* __restrict__ w7, const float* __restrict__ b7,
    const float* __restrict__ mu, const float* __restrict__ sg,
    float* __restrict__ Wh, float* __restrict__ bh, float* __restrict__ slots) {
    __shared__ float A[192], Bt[96], bb[64], bb2[32];
    __shared__ float stats[2];
    int t = threadIdx.x;
    for (int i = t; i < 192; i += 256) A[i] = w0[i];
    for (int i = t; i < 64; i += 256) bb[i] = b0[i];
    __syncthreads();
    const float* wl[5] = {w1, w2, w3, w4, w5};
    const float* bl[5] = {b1, b2, b3, b4, b5};
    int kin = 64;
    for (int l = 0; l < 5; l++) {
        const float* w = wl[l];
        const float* bias = bl[l];
        if (t < 96) {
            int i = t / 32, j = t % 32;
            float acc = 0.f;
            for (int k = 0; k < kin; k++) acc += A[i * kin + k] * w[k * 32 + j];
            Bt[i * 32 + j] = acc;
        } else if (t < 128) {
            int j = t - 96;
            float acc = bias[j];
            for (int k = 0; k < kin; k++) acc += bb[k] * w[k * 32 + j];
            bb2[j] = acc;
        }
        __syncthreads();
        if (t < 96) A[t] = Bt[t];
        if (t < 32) bb[t] = bb2[t];
        __syncthreads();
        kin = 32;
    }
    for (int idx = t; idx < 66 * 128; idx += 256) {
        int i = idx >> 7, j = idx & 127;
        float acc = w7[idx];
        if (i < 3) {
            for (int k = 0; k < 32; k++) acc += A[i * 32 + k] * w7[(66 + k) * 128 + j];
        }
        Wh[idx] = acc;
    }
    for (int j = t; j < 128; j += 256) {
        float acc = b7[j];
        for (int k = 0; k < 32; k++) acc += bb[k] * w7[(66 + k) * 128 + j];
        bh[j] = acc;
    }
    if (t == 0) {
        float s1 = 0.f, s2 = 0.f;
        for (int d = 0; d < 128; d++) { s1 += mu[d]; s2 += sg[d]; }
        float mmu = s1 / 128.f, msg = s2 / 128.f;
        float ss = 0.f;
        for (int d = 0; d < 128; d++) { float e = sg[d] - msg; ss += e * e; }
        stats[0] = mmu;
        stats[1] = sqrtf(64.f * ss / 8191.f);  // std over broadcast 8192, ddof=1
    }
    __syncthreads();
    float mean = stats[0], sd = stats[1];
    // JAX partitionable threefry, 32-bit draw: bits[i] = o0 ^ o1, counter (0, i)
    for (int p = t; p < 8192; p += 256) {
        u32 o0, o1;
        threefry42(0u, (u32)p, o0, o1);
        slots[p] = fmaf(sd, bits_to_normal(o0 ^ o1), mean);
    }
}

// ---------- K2: build hln (f32, layout [32][NB] float4) ----------

__global__ __launch_bounds__(256) void k2_hln(
    const float* __restrict__ inputs, const float* __restrict__ embed,
    const float* __restrict__ Wh, const float* __restrict__ bh,
    const float* __restrict__ g, const float* __restrict__ bbias,
    float4* __restrict__ hln) {
    __shared__ float Whs[66 * 128];
    __shared__ float bhs[128], gs[128], bs_[128];
    int t = threadIdx.x;
    for (int i = t; i < 66 * 128; i += 256) Whs[i] = Wh[i];
    if (t < 128) { bhs[t] = bh[t]; gs[t] = g[t]; bs_[t] = bbias[t]; }
    __syncthreads();
    int r = blockIdx.x * 256 + t;
    float h[128];
#pragma unroll
    for (int j = 0; j < 128; j++) h[j] = bhs[j];
    const float* ip = inputs + (size_t)r * 3;
    const float* ep = embed + (size_t)r * 63;
#pragma unroll 1
    for (int i = 0; i < 3; i++) {
        float v = ip[i];
        const float* wr = &Whs[i * 128];
#pragma unroll
        for (int j = 0; j < 128; j++) h[j] = fmaf(v, wr[j], h[j]);
    }
#pragma unroll 1
    for (int i = 0; i < 63; i++) {
        float v = ep[i];
        const float* wr = &Whs[(3 + i) * 128];
#pragma unroll
        for (int j = 0; j < 128; j++) h[j] = fmaf(v, wr[j], h[j]);
    }
    float s1 = 0.f;
#pragma unroll
    for (int j = 0; j < 128; j++) s1 += h[j];
    float m = s1 * (1.0f / 128.0f);
    float s2 = 0.f;
#pragma unroll
    for (int j = 0; j < 128; j++) { float e = h[j] - m; s2 += e * e; }
    float inv = rsqrtf(s2 * (1.0f / 128.0f) + 1e-5f);
#pragma unroll
    for (int c = 0; c < 32; c++) {
        float4 o;
        o.x = fmaf((h[c * 4 + 0] - m) * inv, gs[c * 4 + 0], bs_[c * 4 + 0]);
        o.y = fmaf((h[c * 4 + 1] - m) * inv, gs[c * 4 + 1], bs_[c * 4 + 1]);
        o.z = fmaf((h[c * 4 + 2] - m) * inv, gs[c * 4 + 2], bs_[c * 4 + 2]);
        o.w = fmaf((h[c * 4 + 3] - m) * inv, gs[c * 4 + 3], bs_[c * 4 + 3]);
        hln[(size_t)c * NB_ + r] = o;
    }
}

// ---------- K3: initial q from slots ----------

__global__ __launch_bounds__(128) void k3_q(
    const float* __restrict__ slots,
    const float* __restrict__ lnsg, const float* __restrict__ lnsb,
    const float* __restrict__ wq, const float* __restrict__ bq,
    const float* __restrict__ wk, const float* __restrict__ bk,
    float* __restrict__ qt, float* __restrict__ qc,
    float* __restrict__ vec, float* __restrict__ den) {
    __shared__ float shA[128];
    __shared__ float red[2];
    int bs = blockIdx.x;
    float x = slots[bs * 128 + threadIdx.x];
    emit_q(x, bs, lnsg, lnsb, wq, bq, wk, bk, qt, qc, vec, den, shA, red);
}

// ---------- K4: attention streaming pass ----------

__global__ __launch_bounds__(256) void k4_attn(
    const float4* __restrict__ hln, const float* __restrict__ qt,
    const float* __restrict__ qc, float* __restrict__ vec, float* __restrict__ den) {
    __shared__ float qlds[1024];
    __shared__ float qcl[8];
    __shared__ __align__(16) float alds[256 * 8];
    __shared__ float vlds[1024];
    __shared__ float dlds[8];
    int t = threadIdx.x;
    int blk = blockIdx.x;
    int b = blk >> 7;  // 128 blocks per batch
    for (int k = t; k < 1024; k += 256) { qlds[k] = qt[b * 1024 + k]; vlds[k] = 0.f; }
    if (t < 8) { qcl[t] = qc[b * 8 + t]; dlds[t] = 0.f; }
    __syncthreads();

    // phase 1: dots + softmax over slots for this thread's row
    int r = blk * 256 + t;
    float dot[8];
#pragma unroll
    for (int s = 0; s < 8; s++) dot[s] = qcl[s];
#pragma unroll 8
    for (int c = 0; c < 32; c++) {
        float4 u = hln[(size_t)c * NB_ + r];
        float f[4] = {u.x, u.y, u.z, u.w};
#pragma unroll
        for (int s = 0; s < 8; s++) {
            const float* qp = &qlds[s * 128 + c * 4];
#pragma unroll
            for (int j = 0; j < 4; j++) dot[s] = fmaf(f[j], qp[j], dot[s]);
        }
    }
    float mx = dot[0];
#pragma unroll
    for (int s = 1; s < 8; s++) mx = fmaxf(mx, dot[s]);
    float ee[8], sum = 0.f;
#pragma unroll
    for (int s = 0; s < 8; s++) { ee[s] = __expf(dot[s] - mx); sum += ee[s]; }
    float invs = 1.0f / sum;
#pragma unroll
    for (int s = 0; s < 8; s++) alds[t * 8 + s] = fmaf(ee[s], invs, 1e-8f);
    __syncthreads();

    // phase 2: vec_s += a_s * hln, den_s += a_s.
    // 8 groups of 32 lanes; lane = granule (4 dims), covers all 8 slots.
    int grp = t >> 5, gr = t & 31;
    float acc[8][4];
#pragma unroll
    for (int s = 0; s < 8; s++)
#pragma unroll
        for (int j = 0; j < 4; j++) acc[s][j] = 0.f;
    float dac[8] = {0.f, 0.f, 0.f, 0.f, 0.f, 0.f, 0.f, 0.f};
    int base = blk * 256 + grp * 32;
#pragma unroll 4
    for (int nn = 0; nn < 32; nn++) {
        int rl = grp * 32 + nn;
        float4 h4 = hln[(size_t)gr * NB_ + base + nn];
        float4 alo = *(const float4*)&alds[rl * 8];
        float4 ahi = *(const float4*)&alds[rl * 8 + 4];
        float a[8] = {alo.x, alo.y, alo.z, alo.w, ahi.x, ahi.y, ahi.z, ahi.w};
        float hv[4] = {h4.x, h4.y, h4.z, h4.w};
#pragma unroll
        for (int s = 0; s < 8; s++) {
#pragma unroll
            for (int j = 0; j < 4; j++) acc[s][j] = fmaf(a[s], hv[j], acc[s][j]);
        }
        if (gr == 0) {
#pragma unroll
            for (int s = 0; s < 8; s++) dac[s] += a[s];
        }
    }
#pragma unroll
    for (int s = 0; s < 8; s++)
#pragma unroll
        for (int j = 0; j < 4; j++)
            atomicAdd(&vlds[s * 128 + gr * 4 + j], acc[s][j]);
    if (gr == 0) {
#pragma unroll
        for (int s = 0; s < 8; s++) atomicAdd(&dlds[s], dac[s]);
    }
    __syncthreads();
    for (int k = t; k < 1024; k += 256) atomicAdd(&vec[b * 1024 + k], vlds[k]);
    if (t < 8) atomicAdd(&den[b * 8 + t], dlds[t]);
}

// ---------- K5: updates -> GRU -> MLP -> slots (+ next q) ----------

__global__ __launch_bounds__(128) void k5_update(
    const float* __restrict__ vec, const float* __restrict__ den,
    const float* __restrict__ wv, const float* __restrict__ bv,
    const float* __restrict__ wih, const float* __restrict__ whh,
    const float* __restrict__ bih, const float* __restrict__ bhh,
    const float* __restrict__ lnfg, const float* __restrict__ lnfb,
    const float* __restrict__ m1w, const float* __restrict__ m1b,
    const float* __restrict__ m2w, const float* __restrict__ m2b,
    float* __restrict__ slots,
    const float* __restrict__ lnsg, const float* __restrict__ lnsb,
    const float* __restrict__ wq, const float* __restrict__ bq,
    const float* __restrict__ wk, const float* __restrict__ bk,
    float* __restrict__ qt, float* __restrict__ qc,
    float* __restrict__ out, int compute_q, int write_out) {
    __shared__ float sA[128], sB[128], sC[128];
    __shared__ float red[2];
    int bs = blockIdx.x, t = threadIdx.x;
    float dv = den[bs];
    sA[t] = vec[bs * 128 + t] / dv;   // u = renormalized attn @ hln
    sC[t] = slots[bs * 128 + t];      // h_prev
    __syncthreads();
    float upd = bv[t];
#pragma unroll 4
    for (int i = 0; i < 128; i++) upd = fmaf(sA[i], wv[i * 128 + t], upd);
    __syncthreads();
    sB[t] = upd;
    __syncthreads();
    float gi[3], gh[3];
#pragma unroll 1
    for (int gx = 0; gx < 3; gx++) {
        int g = gx * 128 + t;
        float a = bih[g], hh = bhh[g];
        const float* wi = &wih[(size_t)g * 128];
        const float* wh = &whh[(size_t)g * 128];
#pragma unroll 4
        for (int d = 0; d < 128; d++) {
            a = fmaf(sB[d], wi[d], a);
            hh = fmaf(sC[d], wh[d], hh);
        }
        gi[gx] = a; gh[gx] = hh;
    }
    float rg = 1.f / (1.f + expf(-(gi[0] + gh[0])));
    float zg = 1.f / (1.f + expf(-(gi[1] + gh[1])));
    float ng = tanhf(fmaf(rg, gh[2], gi[2]));
    float hnew = (1.f - zg) * ng + zg * sC[t];
    float m = block128_sum(hnew, red) * (1.0f / 128.0f);
    float e = hnew - m;
    float var = block128_sum(e * e, red) * (1.0f / 128.0f);
    float inv = rsqrtf(var + 1e-5f);
    __syncthreads();
    sA[t] = fmaf(e * inv, lnfg[t], lnfb[t]);
    __syncthreads();
    float m1 = m1b[t];
#pragma unroll 4
    for (int i = 0; i < 128; i++) m1 = fmaf(sA[i], m1w[i * 128 + t], m1);
    __syncthreads();
    sB[t] = m1;
    __syncthreads();
    float m2 = m2b[t];
#pragma unroll 4
    for (int i = 0; i < 128; i++) m2 = fmaf(sB[i], m2w[i * 128 + t], m2);
    float snew = hnew + m2;
    slots[bs * 128 + t] = snew;
    if (write_out) out[bs * 128 + t] = snew;
    if (compute_q) {
        emit_q(snew, bs, lnsg, lnsb, wq, bq, wk, bk, qt, qc,
               const_cast<float*>(vec), const_cast<float*>(den), sA, red);
    }
}

// ---------- launch ----------

extern "C" void kernel_launch(void* const* d_in, const int* in_sizes, int n_in,
                              void* d_out, int out_size, void* d_ws, size_t ws_size,
                              hipStream_t stream) {
    const float* inputs = (const float*)d_in[0];
    const float* embed  = (const float*)d_in[1];
    const float* mu     = (const float*)d_in[2];
    const float* sg     = (const float*)d_in[3];
    const float* w0 = (const float*)d_in[4];  const float* b0 = (const float*)d_in[5];
    const float* w1 = (const float*)d_in[6];  const float* b1 = (const float*)d_in[7];
    const float* w2 = (const float*)d_in[8];  const float* b2 = (const float*)d_in[9];
    const float* w3 = (const float*)d_in[10]; const float* b3 = (const float*)d_in[11];
    const float* w4 = (const float*)d_in[12]; const float* b4 = (const float*)d_in[13];
    const float* w5 = (const float*)d_in[14]; const float* b5 = (const float*)d_in[15];
    const float* w7 = (const float*)d_in[16]; const float* b7 = (const float*)d_in[17];
    const float* wq = (const float*)d_in[18]; const float* bq = (const float*)d_in[19];
    const float* wk = (const float*)d_in[20]; const float* bk = (const float*)d_in[21];
    const float* wv = (const float*)d_in[22]; const float* bv = (const float*)d_in[23];
    const float* ln_in_g = (const float*)d_in[24]; const float* ln_in_b = (const float*)d_in[25];
    const float* ln_sl_g = (const float*)d_in[26]; const float* ln_sl_b = (const float*)d_in[27];
    const float* ln_ff_g = (const float*)d_in[28]; const float* ln_ff_b = (const float*)d_in[29];
    const float* gwih = (const float*)d_in[30]; const float* gwhh = (const float*)d_in[31];
    const float* gbih = (const float*)d_in[32]; const float* gbhh = (const float*)d_in[33];
    const float* m1w = (const float*)d_in[34]; const float* m1b = (const float*)d_in[35];
    const float* m2w = (const float*)d_in[36]; const float* m2b = (const float*)d_in[37];

    char* ws = (char*)d_ws;
    float4* hln = (float4*)ws;
    size_t off = (size_t)32 * NB_ * 16;  // 128 MB f32 hln
    float* Wh    = (float*)(ws + off); off += 66 * 128 * 4;
    float* bh    = (float*)(ws + off); off += 128 * 4;
    float* slots = (float*)(ws + off); off += 64 * 128 * 4;
    float* qt    = (float*)(ws + off); off += 64 * 128 * 4;
    float* qc    = (float*)(ws + off); off += 64 * 4;
    float* vec   = (float*)(ws + off); off += 64 * 128 * 4;
    float* den   = (float*)(ws + off); off += 64 * 4;

    k1_setup<<<1, 256, 0, stream>>>(w0, b0, w1, b1, w2, b2, w3, b3, w4, b4, w5, b5,
                                    w7, b7, mu, sg, Wh, bh, slots);
    k2_hln<<<NB_ / 256, 256, 0, stream>>>(inputs, embed, Wh, bh, ln_in_g, ln_in_b, hln);
    k3_q<<<64, 128, 0, stream>>>(slots, ln_sl_g, ln_sl_b, wq, bq, wk, bk, qt, qc, vec, den);
    for (int it = 0; it < 3; it++) {
        k4_attn<<<1024, 256, 0, stream>>>(hln, qt, qc, vec, den);
        k5_update<<<64, 128, 0, stream>>>(vec, den, wv, bv, gwih, gwhh, gbih, gbhh,
                                          ln_ff_g, ln_ff_b, m1w, m1b, m2w, m2b, slots,
                                          ln_sl_g, ln_sl_b, wq, bq, wk, bk, qt, qc,
                                          (float*)d_out, (it < 2) ? 1 : 0, (it == 2) ? 1 : 0);
    }
}

// Round 6
// 508.315 us; speedup vs baseline: 1.1656x; 1.1656x over previous
//
#include <hip/hip_runtime.h>

// SlotAttention fused implementation (f32 hln, row-major).
//   - 6-layer linear stack folded into effective 66->128 affine (Wh, bh).
//   - k,v projections folded out of the N dimension:
//       q.k_n = (wk@q) . hln_n + q.bk ;  updates = (sum attn*hln)/den @ wv + bv
//   - hln = LN(h) materialized f32 row-major [NB][128].
//   - slot init: JAX partitionable threefry: bits[i] = o0^o1, counter (0,i).
//   - k2: 4 threads/row, regs h4[8], swizzled-LDS Wh (stride 144, quarter*36).
//   - k4: 512 blocks x 8 tiles(64 rows); tile staged to LDS once (coalesced),
//         ph1 dots+softmax (4 lanes/row), ph2 (slot,quad)-per-thread reg accum.

#define B_  8
#define N_  32768
#define NB_ (B_ * N_)   // 262144 rows
#define D_  128
#define S_  8

typedef unsigned int u32;

// threefry2x32, key = (0, 42)  (jax.random.key(42))
__device__ inline void threefry42(u32 c0, u32 c1, u32& o0, u32& o1) {
    const u32 k0 = 0u, k1 = 42u, k2 = 0x1BD11BDAu ^ 0u ^ 42u;
    const u32 ks[3] = {k0, k1, k2};
    u32 x0 = c0 + k0, x1 = c1 + k1;
    const int rA[4] = {13, 15, 26, 6}, rB[4] = {17, 29, 16, 24};
#pragma unroll
    for (int i = 0; i < 5; i++) {
#pragma unroll
        for (int k = 0; k < 4; k++) {
            int r = (i & 1) ? rB[k] : rA[k];
            x0 += x1;
            x1 = (x1 << r) | (x1 >> (32 - r));
            x1 ^= x0;
        }
        x0 += ks[(i + 1) % 3];
        x1 += ks[(i + 2) % 3] + (u32)(i + 1);
    }
    o0 = x0; o1 = x1;
}

// jax uniform(-0.99999994, 1) -> sqrt(2)*erfinv  (XLA ErfInv32 polynomial)
__device__ inline float bits_to_normal(u32 b) {
    float f = __uint_as_float((b >> 9) | 0x3f800000u) - 1.0f;  // [0,1)
    const float lo = -0.99999994f;
    float r = fmaxf(lo, f * 1.99999994f + lo);
    float w = -log1pf(-r * r);
    float p;
    if (w < 5.0f) {
        w -= 2.5f;
        p = 2.81022636e-08f;
        p = fmaf(p, w, 3.43273939e-07f);
        p = fmaf(p, w, -3.5233877e-06f);
        p = fmaf(p, w, -4.39150654e-06f);
        p = fmaf(p, w, 0.00021858087f);
        p = fmaf(p, w, -0.00125372503f);
        p = fmaf(p, w, -0.00417768164f);
        p = fmaf(p, w, 0.246640727f);
        p = fmaf(p, w, 1.50140941f);
    } else {
        w = sqrtf(w) - 3.0f;
        p = -0.000200214257f;
        p = fmaf(p, w, 0.000100950558f);
        p = fmaf(p, w, 0.00134934322f);
        p = fmaf(p, w, -0.00367342844f);
        p = fmaf(p, w, 0.00573950773f);
        p = fmaf(p, w, -0.0076224613f);
        p = fmaf(p, w, 0.00943887047f);
        p = fmaf(p, w, 1.00167406f);
        p = fmaf(p, w, 2.83297682f);
    }
    return 1.41421356f * (p * r);
}

// 128-thread block sum (2 waves), red = 2-float shared scratch
__device__ inline float block128_sum(float v, float* red) {
#pragma unroll
    for (int o = 32; o; o >>= 1) v += __shfl_down(v, o);
    __syncthreads();
    if ((threadIdx.x & 63) == 0) red[threadIdx.x >> 6] = v;
    __syncthreads();
    return red[0] + red[1];
}

// LN(slot row) -> q -> qtilde(scaled), qc(scaled); zero vec/den accumulators.
__device__ void emit_q(float x, int bs,
                       const float* lnsg, const float* lnsb,
                       const float* wq, const float* bq,
                       const float* wk, const float* bk,
                       float* qt, float* qc, float* vec, float* den,
                       float* shA, float* red) {
    int t = threadIdx.x;
    float m = block128_sum(x, red) * (1.0f / 128.0f);
    float e = x - m;
    float var = block128_sum(e * e, red) * (1.0f / 128.0f);
    float inv = rsqrtf(var + 1e-5f);
    __syncthreads();
    shA[t] = fmaf(e * inv, lnsg[t], lnsb[t]);
    __syncthreads();
    float q = bq[t];
#pragma unroll 4
    for (int i = 0; i < 128; i++) q = fmaf(shA[i], wq[i * 128 + t], q);
    __syncthreads();
    shA[t] = q;
    __syncthreads();
    float a2 = 0.f;
#pragma unroll 4
    for (int j = 0; j < 128; j++) a2 = fmaf(wk[t * 128 + j], shA[j], a2);
    const float scale = 0.08838834764831845f;  // 128^-0.5
    qt[bs * 128 + t] = a2 * scale;
    float pr = block128_sum(shA[t] * bk[t], red);
    if (t == 0) { qc[bs] = pr * scale; den[bs] = 0.f; }
    vec[bs * 128 + t] = 0.f;
}

// ---------- K1: fold weights, init slots ----------

__global__ __launch_bounds__(256) void k1_setup(
    const float* __restrict__ w0, const float* __restrict__ b0,
    const float* __restrict__ w1, const float* __restrict__ b1,
    const float* __restrict__ w2, const float* __restrict__ b2,
    const float* __restrict__ w3, const float* __restrict__ b3,
    const float* __restrict__ w4, const float* __restrict__ b4,
    const float* __restrict__ w5, const float* __restrict__ b5,
    const float* __restrict__ w7, const float* __restrict__ b7,
    const float* __restrict__ mu, const float* __restrict__ sg,
    float* __restrict__ Wh, float* __restrict__ bh, float* __restrict__ slots) {
    __shared__ float A[192], Bt[96], bb[64], bb2[32];
    __shared__ float stats[2];
    int t = threadIdx.x;
    for (int i = t; i < 192; i += 256) A[i] = w0[i];
    for (int i = t; i < 64; i += 256) bb[i] = b0[i];
    __syncthreads();
    const float* wl[5] = {w1, w2, w3, w4, w5};
    const float* bl[5] = {b1, b2, b3, b4, b5};
    int kin = 64;
    for (int l = 0; l < 5; l++) {
        const float* w = wl[l];
        const float* bias = bl[l];
        if (t < 96) {
            int i = t / 32, j = t % 32;
            float acc = 0.f;
            for (int k = 0; k < kin; k++) acc += A[i * kin + k] * w[k * 32 + j];
            Bt[i * 32 + j] = acc;
        } else if (t < 128) {
            int j = t - 96;
            float acc = bias[j];
            for (int k = 0; k < kin; k++) acc += bb[k] * w[k * 32 + j];
            bb2[j] = acc;
        }
        __syncthreads();
        if (t < 96) A[t] = Bt[t];
        if (t < 32) bb[t] = bb2[t];
        __syncthreads();
        kin = 32;
    }
    for (int idx = t; idx < 66 * 128; idx += 256) {
        int i = idx >> 7, j = idx & 127;
        float acc = w7[idx];
        if (i < 3) {
            for (int k = 0; k < 32; k++) acc += A[i * 32 + k] * w7[(66 + k) * 128 + j];
        }
        Wh[idx] = acc;
    }
    for (int j = t; j < 128; j += 256) {
        float acc = b7[j];
        for (int k = 0; k < 32; k++) acc += bb[k] * w7[(66 + k) * 128 + j];
        bh[j] = acc;
    }
    if (t == 0) {
        float s1 = 0.f, s2 = 0.f;
        for (int d = 0; d < 128; d++) { s1 += mu[d]; s2 += sg[d]; }
        float mmu = s1 / 128.f, msg = s2 / 128.f;
        float ss = 0.f;
        for (int d = 0; d < 128; d++) { float e = sg[d] - msg; ss += e * e; }
        stats[0] = mmu;
        stats[1] = sqrtf(64.f * ss / 8191.f);  // std over broadcast 8192, ddof=1
    }
    __syncthreads();
    float mean = stats[0], sd = stats[1];
    for (int p = t; p < 8192; p += 256) {
        u32 o0, o1;
        threefry42(0u, (u32)p, o0, o1);
        slots[p] = fmaf(sd, bits_to_normal(o0 ^ o1), mean);
    }
}

// ---------- K2: build hln (f32 row-major [NB][128]) ----------
// 64 rows/block, 4 threads/row, h in 8xfloat4 regs, swizzled Wh in LDS.

__global__ __launch_bounds__(256) void k2_hln(
    const float* __restrict__ inputs, const float* __restrict__ embed,
    const float* __restrict__ Wh, const float* __restrict__ bh,
    const float* __restrict__ g, const float* __restrict__ bbias,
    float* __restrict__ hln) {
    __shared__ __align__(16) float Whs[66 * 144];   // [i][qq*36 + j], 38016 B
    __shared__ float ebuf[64 * 66];                 // 16896 B
    __shared__ __align__(16) float bhs[128], gs[128], bs_[128];
    int t = threadIdx.x;
    for (int gi = t; gi < 66 * 128; gi += 256) {
        int i = gi >> 7, d = gi & 127;
        Whs[i * 144 + (d >> 5) * 36 + (d & 31)] = Wh[gi];
    }
    if (t < 128) { bhs[t] = bh[t]; gs[t] = g[t]; bs_[t] = bbias[t]; }
    size_t rbase = (size_t)blockIdx.x * 64;
    if (t < 192) ebuf[(t / 3) * 66 + (t % 3)] = inputs[rbase * 3 + t];
    for (int idx = t; idx < 64 * 63; idx += 256) {
        int rr = idx / 63, i = idx - rr * 63;
        ebuf[rr * 66 + 3 + i] = embed[rbase * 63 + idx];
    }
    __syncthreads();
    int rr = t >> 2, qq = t & 3;
    float4 h4[8];
#pragma unroll
    for (int jj = 0; jj < 8; jj++) h4[jj] = *(const float4*)&bhs[qq * 32 + jj * 4];
    const float* ev = &ebuf[rr * 66];
#pragma unroll 2
    for (int i = 0; i < 66; i++) {
        float v = ev[i];
        const float4* wrow = (const float4*)Whs + i * 36 + qq * 9;
#pragma unroll
        for (int jj = 0; jj < 8; jj++) {
            float4 w = wrow[jj];
            h4[jj].x = fmaf(v, w.x, h4[jj].x);
            h4[jj].y = fmaf(v, w.y, h4[jj].y);
            h4[jj].z = fmaf(v, w.z, h4[jj].z);
            h4[jj].w = fmaf(v, w.w, h4[jj].w);
        }
    }
    float s1 = 0.f;
#pragma unroll
    for (int jj = 0; jj < 8; jj++) s1 += h4[jj].x + h4[jj].y + h4[jj].z + h4[jj].w;
    s1 += __shfl_xor(s1, 1);
    s1 += __shfl_xor(s1, 2);
    float m = s1 * (1.0f / 128.0f);
    float s2 = 0.f;
#pragma unroll
    for (int jj = 0; jj < 8; jj++) {
        float ex = h4[jj].x - m, ey = h4[jj].y - m, ez = h4[jj].z - m, ew = h4[jj].w - m;
        s2 += ex * ex + ey * ey + ez * ez + ew * ew;
    }
    s2 += __shfl_xor(s2, 1);
    s2 += __shfl_xor(s2, 2);
    float inv = rsqrtf(s2 * (1.0f / 128.0f) + 1e-5f);
    float4* out4 = (float4*)hln + (rbase + rr) * 32 + qq * 8;
#pragma unroll
    for (int jj = 0; jj < 8; jj++) {
        float4 gg = *(const float4*)&gs[qq * 32 + jj * 4];
        float4 bb4 = *(const float4*)&bs_[qq * 32 + jj * 4];
        float4 o;
        o.x = fmaf((h4[jj].x - m) * inv, gg.x, bb4.x);
        o.y = fmaf((h4[jj].y - m) * inv, gg.y, bb4.y);
        o.z = fmaf((h4[jj].z - m) * inv, gg.z, bb4.z);
        o.w = fmaf((h4[jj].w - m) * inv, gg.w, bb4.w);
        out4[jj] = o;
    }
}

// ---------- K3: initial q from slots ----------

__global__ __launch_bounds__(128) void k3_q(
    const float* __restrict__ slots,
    const float* __restrict__ lnsg, const float* __restrict__ lnsb,
    const float* __restrict__ wq, const float* __restrict__ bq,
    const float* __restrict__ wk, const float* __restrict__ bk,
    float* __restrict__ qt, float* __restrict__ qc,
    float* __restrict__ vec, float* __restrict__ den) {
    __shared__ float shA[128];
    __shared__ float red[2];
    int bs = blockIdx.x;
    float x = slots[bs * 128 + threadIdx.x];
    emit_q(x, bs, lnsg, lnsb, wq, bq, wk, bk, qt, qc, vec, den, shA, red);
}

// ---------- K4: attention pass (LDS-tiled, single hln read) ----------
// 512 blocks: 64 per batch, each owns 512 rows = 8 tiles of 64.

__global__ __launch_bounds__(256) void k4_attn(
    const float4* __restrict__ hln4, const float* __restrict__ qt,
    const float* __restrict__ qc, float* __restrict__ vec, float* __restrict__ den) {
    __shared__ __align__(16) float tile[64 * 144];  // [row][qq*36+j], 36864 B
    __shared__ __align__(16) float qswz[8 * 144];   // swizzled q, 4608 B
    __shared__ __align__(16) float alds[64 * 8];    // attn weights per tile
    __shared__ float qcl[8];
    int t = threadIdx.x;
    int blk = blockIdx.x;
    int b = blk >> 6;
    int slab = blk & 63;
    size_t row0 = (size_t)b * N_ + (size_t)slab * 512;
    const float4* src = hln4 + row0 * 32;

    for (int i = t; i < 1024; i += 256) {
        int s = i >> 7, d = i & 127;
        qswz[s * 144 + (d >> 5) * 36 + (d & 31)] = qt[b * 1024 + i];
    }
    if (t < 8) qcl[t] = qc[b * 8 + t];

    int rr = t >> 2, qq = t & 3;          // ph1 roles
    int so = t >> 5, c = t & 31;          // ph2 roles
    int cq = c >> 3, cj = c & 7;
    float4 acc = {0.f, 0.f, 0.f, 0.f};
    float dden = 0.f;
    float4 st[8];
#pragma unroll
    for (int k = 0; k < 8; k++) st[k] = src[t + k * 256];
#pragma unroll
    for (int k = 0; k < 8; k++) {
        int idx = t + k * 256;
        int row = idx >> 5, c4 = idx & 31;
        *(float4*)&tile[(row * 36 + (c4 >> 3) * 9 + (c4 & 7)) * 4] = st[k];
    }
    __syncthreads();

    for (int tt = 0; tt < 8; tt++) {
        if (tt < 7) {
            const float4* sp = src + (size_t)(tt + 1) * 2048;
#pragma unroll
            for (int k = 0; k < 8; k++) st[k] = sp[t + k * 256];
        }
        // ---- phase 1: dots + softmax (4 lanes per row) ----
        float p[8];
#pragma unroll
        for (int s = 0; s < 8; s++) p[s] = 0.f;
#pragma unroll
        for (int jj = 0; jj < 8; jj++) {
            float4 hv = *(const float4*)&tile[(rr * 36 + qq * 9 + jj) * 4];
#pragma unroll
            for (int s = 0; s < 8; s++) {
                float4 qv = *(const float4*)&qswz[(s * 36 + qq * 9 + jj) * 4];
                p[s] = fmaf(hv.x, qv.x, p[s]);
                p[s] = fmaf(hv.y, qv.y, p[s]);
                p[s] = fmaf(hv.z, qv.z, p[s]);
                p[s] = fmaf(hv.w, qv.w, p[s]);
            }
        }
#pragma unroll
        for (int s = 0; s < 8; s++) {
            float v = p[s];
            v += __shfl_xor(v, 1);
            v += __shfl_xor(v, 2);
            p[s] = v + qcl[s];
        }
        float mx = p[0];
#pragma unroll
        for (int s = 1; s < 8; s++) mx = fmaxf(mx, p[s]);
        float sum = 0.f;
#pragma unroll
        for (int s = 0; s < 8; s++) { p[s] = __expf(p[s] - mx); sum += p[s]; }
        float invs = 1.0f / sum;
        if (qq == 0) {
            float4 a0, a1;
            a0.x = fmaf(p[0], invs, 1e-8f); a0.y = fmaf(p[1], invs, 1e-8f);
            a0.z = fmaf(p[2], invs, 1e-8f); a0.w = fmaf(p[3], invs, 1e-8f);
            a1.x = fmaf(p[4], invs, 1e-8f); a1.y = fmaf(p[5], invs, 1e-8f);
            a1.z = fmaf(p[6], invs, 1e-8f); a1.w = fmaf(p[7], invs, 1e-8f);
            *(float4*)&alds[rr * 8] = a0;
            *(float4*)&alds[rr * 8 + 4] = a1;
        }
        __syncthreads();
        // ---- phase 2: acc(s, quad c) += a_s(r) * h(r, quad c) ----
#pragma unroll 4
        for (int r = 0; r < 64; r++) {
            float av = alds[r * 8 + so];
            float4 hv = *(const float4*)&tile[(r * 36 + cq * 9 + cj) * 4];
            acc.x = fmaf(av, hv.x, acc.x);
            acc.y = fmaf(av, hv.y, acc.y);
            acc.z = fmaf(av, hv.z, acc.z);
            acc.w = fmaf(av, hv.w, acc.w);
            if (c == 0) dden += av;
        }
        __syncthreads();
        if (tt < 7) {
#pragma unroll
            for (int k = 0; k < 8; k++) {
                int idx = t + k * 256;
                int row = idx >> 5, c4 = idx & 31;
                *(float4*)&tile[(row * 36 + (c4 >> 3) * 9 + (c4 & 7)) * 4] = st[k];
            }
            __syncthreads();
        }
    }
    float* vp = vec + b * 1024 + so * 128 + c * 4;
    atomicAdd(vp + 0, acc.x);
    atomicAdd(vp + 1, acc.y);
    atomicAdd(vp + 2, acc.z);
    atomicAdd(vp + 3, acc.w);
    if (c == 0) atomicAdd(&den[b * 8 + so], dden);
}

// ---------- K5: updates -> GRU -> MLP -> slots (+ next q) ----------

__global__ __launch_bounds__(128) void k5_update(
    const float* __restrict__ vec, const float* __restrict__ den,
    const float* __restrict__ wv, const float* __restrict__ bv,
    const float* __restrict__ wih, const float* __restrict__ whh,
    const float* __restrict__ bih, const float* __restrict__ bhh,
    const float* __restrict__ lnfg, const float* __restrict__ lnfb,
    const float* __restrict__ m1w, const float* __restrict__ m1b,
    const float* __restrict__ m2w, const float* __restrict__ m2b,
    float* __restrict__ slots,
    const float* __restrict__ lnsg, const float* __restrict__ lnsb,
    const float* __restrict__ wq, const float* __restrict__ bq,
    const float* __restrict__ wk, const float* __restrict__ bk,
    float* __restrict__ qt, float* __restrict__ qc,
    float* __restrict__ out, int compute_q, int write_out) {
    __shared__ float sA[128], sB[128], sC[128];
    __shared__ float red[2];
    int bs = blockIdx.x, t = threadIdx.x;
    float dv = den[bs];
    sA[t] = vec[bs * 128 + t] / dv;
    sC[t] = slots[bs * 128 + t];
    __syncthreads();
    float upd = bv[t];
#pragma unroll 4
    for (int i = 0; i < 128; i++) upd = fmaf(sA[i], wv[i * 128 + t], upd);
    __syncthreads();
    sB[t] = upd;
    __syncthreads();
    float gi[3], gh[3];
#pragma unroll 1
    for (int gx = 0; gx < 3; gx++) {
        int g = gx * 128 + t;
        float a = bih[g], hh = bhh[g];
        const float* wi = &wih[(size_t)g * 128];
        const float* wh = &whh[(size_t)g * 128];
#pragma unroll 4
        for (int d = 0; d < 128; d++) {
            a = fmaf(sB[d], wi[d], a);
            hh = fmaf(sC[d], wh[d], hh);
        }
        gi[gx] = a; gh[gx] = hh;
    }
    float rg = 1.f / (1.f + expf(-(gi[0] + gh[0])));
    float zg = 1.f / (1.f + expf(-(gi[1] + gh[1])));
    float ng = tanhf(fmaf(rg, gh[2], gi[2]));
    float hnew = (1.f - zg) * ng + zg * sC[t];
    float m = block128_sum(hnew, red) * (1.0f / 128.0f);
    float e = hnew - m;
    float var = block128_sum(e * e, red) * (1.0f / 128.0f);
    float inv = rsqrtf(var + 1e-5f);
    __syncthreads();
    sA[t] = fmaf(e * inv, lnfg[t], lnfb[t]);
    __syncthreads();
    float m1 = m1b[t];
#pragma unroll 4
    for (int i = 0; i < 128; i++) m1 = fmaf(sA[i], m1w[i * 128 + t], m1);
    __syncthreads();
    sB[t] = m1;
    __syncthreads();
    float m2 = m2b[t];
#pragma unroll 4
    for (int i = 0; i < 128; i++) m2 = fmaf(sB[i], m2w[i * 128 + t], m2);
    float snew = hnew + m2;
    slots[bs * 128 + t] = snew;
    if (write_out) out[bs * 128 + t] = snew;
    if (compute_q) {
        emit_q(snew, bs, lnsg, lnsb, wq, bq, wk, bk, qt, qc,
               const_cast<float*>(vec), const_cast<float*>(den), sA, red);
    }
}

// ---------- launch ----------

extern "C" void kernel_launch(void* const* d_in, const int* in_sizes, int n_in,
                              void* d_out, int out_size, void* d_ws, size_t ws_size,
                              hipStream_t stream) {
    const float* inputs = (const float*)d_in[0];
    const float* embed  = (const float*)d_in[1];
    const float* mu     = (const float*)d_in[2];
    const float* sg     = (const float*)d_in[3];
    const float* w0 = (const float*)d_in[4];  const float* b0 = (const float*)d_in[5];
    const float* w1 = (const float*)d_in[6];  const float* b1 = (const float*)d_in[7];
    const float* w2 = (const float*)d_in[8];  const float* b2 = (const float*)d_in[9];
    const float* w3 = (const float*)d_in[10]; const float* b3 = (const float*)d_in[11];
    const float* w4 = (const float*)d_in[12]; const float* b4 = (const float*)d_in[13];
    const float* w5 = (const float*)d_in[14]; const float* b5 = (const float*)d_in[15];
    const float* w7 = (const float*)d_in[16]; const float* b7 = (const float*)d_in[17];
    const float* wq = (const float*)d_in[18]; const float* bq = (const float*)d_in[19];
    const float* wk = (const float*)d_in[20]; const float* bk = (const float*)d_in[21];
    const float* wv = (const float*)d_in[22]; const float* bv = (const float*)d_in[23];
    const float* ln_in_g = (const float*)d_in[24]; const float* ln_in_b = (const float*)d_in[25];
    const float* ln_sl_g = (const float*)d_in[26]; const float* ln_sl_b = (const float*)d_in[27];
    const float* ln_ff_g = (const float*)d_in[28]; const float* ln_ff_b = (const float*)d_in[29];
    const float* gwih = (const float*)d_in[30]; const float* gwhh = (const float*)d_in[31];
    const float* gbih = (const float*)d_in[32]; const float* gbhh = (const float*)d_in[33];
    const float* m1w = (const float*)d_in[34]; const float* m1b = (const float*)d_in[35];
    const float* m2w = (const float*)d_in[36]; const float* m2b = (const float*)d_in[37];

    char* ws = (char*)d_ws;
    float* hln = (float*)ws;
    size_t off = (size_t)NB_ * 128 * 4;  // 128 MB f32 hln row-major
    float* Wh    = (float*)(ws + off); off += 66 * 128 * 4;
    float* bh    = (float*)(ws + off); off += 128 * 4;
    float* slots = (float*)(ws + off); off += 64 * 128 * 4;
    float* qt    = (float*)(ws + off); off += 64 * 128 * 4;
    float* qc    = (float*)(ws + off); off += 64 * 4;
    float* vec   = (float*)(ws + off); off += 64 * 128 * 4;
    float* den   = (float*)(ws + off); off += 64 * 4;

    k1_setup<<<1, 256, 0, stream>>>(w0, b0, w1, b1, w2, b2, w3, b3, w4, b4, w5, b5,
                                    w7, b7, mu, sg, Wh, bh, slots);
    k2_hln<<<NB_ / 64, 256, 0, stream>>>(inputs, embed, Wh, bh, ln_in_g, ln_in_b, hln);
    k3_q<<<64, 128, 0, stream>>>(slots, ln_sl_g, ln_sl_b, wq, bq, wk, bk, qt, qc, vec, den);
    for (int it = 0; it < 3; it++) {
        k4_attn<<<512, 256, 0, stream>>>((const float4*)hln, qt, qc, vec, den);
        k5_update<<<64, 128, 0, stream>>>(vec, den, wv, bv, gwih, gwhh, gbih, gbhh,
                                          ln_ff_g, ln_ff_b, m1w, m1b, m2w, m2b, slots,
                                          ln_sl_g, ln_sl_b, wq, bq, wk, bk, qt, qc,
                                          (float*)d_out, (it < 2) ? 1 : 0, (it == 2) ? 1 : 0);
    }
}